// Round 7
// baseline (242.905 us; speedup 1.0000x reference)
//
#include <hip/hip_runtime.h>
#include <hip/hip_bf16.h>

#define VOCAB 100000
#define D 300
#define B 128
#define S 2048
#define T 4

// workspace layout (float offsets)
#define WS_V      0                    // packed projection vectors [300][12]
#define WS_WTWU   3600                 // Wt@Wu [300]
#define WS_WT2WU  3900                 // Wt^2@Wu [300]
#define WS_WTWO   4200                 // Wt@Wo [300][3]
#define WS_W2WO   5100                 // Wt^2@Wo [300][3]
#define WS_WT3WO  6000                 // Wt^3@Wo [300][3]
#define WS_CONST  6900                 // b_tr dot consts [16]
#define WS_PROJ   7940                 // proj [VOCAB][12] (float4-aligned: 7940*4%16==0)

// channels: 0=Wa 1=Wu 2=WtWu 3..5=Wo 6..8=WtWo 9..11=Wt2Wo
// consts:   0=btr.Wu 1=btr.WtWu 2..4=btr.Wo 5..7=btr.WtWo 8..10=btr.Wt2Wo
// dscal(LDS in k_hops): 0=u0.Wu 1=u0.WtWu 2=u0.Wt2Wu 3..5=u0.Wt3Wo_c

__device__ __forceinline__ float wave_red(float x) {
    #pragma unroll
    for (int m = 1; m < 64; m <<= 1) x += __shfl_xor(x, m, 64);
    return x;   // full sum present in ALL lanes (butterfly)
}

// fast tanh for moderate args (|x| small here): tanh(x) = 1 - 2/(e^2x + 1)
__device__ __forceinline__ float fast_tanh(float x) {
    float e = __expf(2.0f * x);
    return 1.0f - 2.0f / (e + 1.0f);
}

// ---------------------------------------------------------------------------
// Level 1: WtWu[i] = Wtr[i]·Wu ; WtWo[i][c] = Wtr[i]·Wo_c.  One row per block.
// ---------------------------------------------------------------------------
__global__ __launch_bounds__(64) void k_derive1(const float* __restrict__ Watt,
                                                const float* __restrict__ Wtr,
                                                const float* __restrict__ Wout,
                                                float* __restrict__ ws) {
    int i = blockIdx.x, lane = threadIdx.x;
    const float* wrow = Wtr + (size_t)i * D;
    float au = 0.f, a0 = 0.f, a1 = 0.f, a2 = 0.f;
    for (int j = lane; j < D; j += 64) {
        float w = wrow[j];
        au += w * Watt[D + j];
        a0 += w * Wout[j * 3 + 0];
        a1 += w * Wout[j * 3 + 1];
        a2 += w * Wout[j * 3 + 2];
    }
    au = wave_red(au); a0 = wave_red(a0); a1 = wave_red(a1); a2 = wave_red(a2);
    if (lane == 0) {
        ws[WS_WTWU + i] = au;
        ws[WS_WTWO + i * 3 + 0] = a0;
        ws[WS_WTWO + i * 3 + 1] = a1;
        ws[WS_WTWO + i * 3 + 2] = a2;
    }
}

// ---------------------------------------------------------------------------
// Level 2: Wt2Wu = Wt@WtWu ; W2Wo = Wt@WtWo ; pack V row i (depth<=2 only).
// ---------------------------------------------------------------------------
__global__ __launch_bounds__(64) void k_derive2(const float* __restrict__ Watt,
                                                const float* __restrict__ Wtr,
                                                const float* __restrict__ Wout,
                                                float* __restrict__ ws) {
    int i = blockIdx.x, lane = threadIdx.x;
    const float* wrow = Wtr + (size_t)i * D;
    float au = 0.f, a0 = 0.f, a1 = 0.f, a2 = 0.f;
    for (int j = lane; j < D; j += 64) {
        float w = wrow[j];
        au += w * ws[WS_WTWU + j];
        a0 += w * ws[WS_WTWO + j * 3 + 0];
        a1 += w * ws[WS_WTWO + j * 3 + 1];
        a2 += w * ws[WS_WTWO + j * 3 + 2];
    }
    au = wave_red(au); a0 = wave_red(a0); a1 = wave_red(a1); a2 = wave_red(a2);
    if (lane == 0) {
        ws[WS_WT2WU + i] = au;
        ws[WS_W2WO + i * 3 + 0] = a0;
        ws[WS_W2WO + i * 3 + 1] = a1;
        ws[WS_W2WO + i * 3 + 2] = a2;
    }
    // pack V[i][0..11] — a0..a2 live in every lane after butterfly
    if (lane < 12) {
        float val;
        if      (lane == 0)  val = Watt[i];
        else if (lane == 1)  val = Watt[D + i];
        else if (lane == 2)  val = ws[WS_WTWU + i];
        else if (lane < 6)   val = Wout[i * 3 + (lane - 3)];
        else if (lane < 9)   val = ws[WS_WTWO + i * 3 + (lane - 6)];
        else if (lane == 9)  val = a0;
        else if (lane == 10) val = a1;
        else                 val = a2;
        ws[WS_V + i * 12 + lane] = val;
    }
}

// ---------------------------------------------------------------------------
// Level 3: blocks 0..299: Wt3Wo[i] = Wtr[i]·W2Wo.  Block 300: btr consts.
// ---------------------------------------------------------------------------
__global__ __launch_bounds__(64) void k_derive3(const float* __restrict__ Watt,
                                                const float* __restrict__ Wtr,
                                                const float* __restrict__ Wout,
                                                const float* __restrict__ btr,
                                                float* __restrict__ ws) {
    int lane = threadIdx.x;
    if (blockIdx.x < D) {
        int i = blockIdx.x;
        const float* wrow = Wtr + (size_t)i * D;
        float a0 = 0.f, a1 = 0.f, a2 = 0.f;
        for (int j = lane; j < D; j += 64) {
            float w = wrow[j];
            a0 += w * ws[WS_W2WO + j * 3 + 0];
            a1 += w * ws[WS_W2WO + j * 3 + 1];
            a2 += w * ws[WS_W2WO + j * 3 + 2];
        }
        a0 = wave_red(a0); a1 = wave_red(a1); a2 = wave_red(a2);
        if (lane == 0) {
            ws[WS_WT3WO + i * 3 + 0] = a0;
            ws[WS_WT3WO + i * 3 + 1] = a1;
            ws[WS_WT3WO + i * 3 + 2] = a2;
        }
    } else {
        float acc[11];
        #pragma unroll
        for (int k = 0; k < 11; ++k) acc[k] = 0.f;
        for (int i = lane; i < D; i += 64) {
            float bt = btr[i];
            acc[0]  += bt * Watt[D + i];
            acc[1]  += bt * ws[WS_WTWU + i];
            acc[2]  += bt * Wout[i * 3 + 0];
            acc[3]  += bt * Wout[i * 3 + 1];
            acc[4]  += bt * Wout[i * 3 + 2];
            acc[5]  += bt * ws[WS_WTWO + i * 3 + 0];
            acc[6]  += bt * ws[WS_WTWO + i * 3 + 1];
            acc[7]  += bt * ws[WS_WTWO + i * 3 + 2];
            acc[8]  += bt * ws[WS_W2WO + i * 3 + 0];
            acc[9]  += bt * ws[WS_W2WO + i * 3 + 1];
            acc[10] += bt * ws[WS_W2WO + i * 3 + 2];
        }
        #pragma unroll
        for (int k = 0; k < 11; ++k) acc[k] = wave_red(acc[k]);
        if (lane == 0) {
            #pragma unroll
            for (int k = 0; k < 11; ++k) ws[WS_CONST + k] = acc[k];
        }
    }
}

// ---------------------------------------------------------------------------
// K5: vocab projection, row-per-lane. Lane owns one row: 75 float4 reads
// (sequential per lane -> 64B lines fully consumed over 4 iters via L1),
// V operand wave-uniform -> scalar loads. unroll 15 for deep load pipelining
// (occupancy is ~1.5 waves/SIMD; latency hiding is ILP-driven).
// ---------------------------------------------------------------------------
__global__ __launch_bounds__(256) void k_proj(const float* __restrict__ E,
                                              const float* __restrict__ Vg,
                                              float* __restrict__ proj) {
    int lane = threadIdx.x & 63;
    int wid  = (blockIdx.x * blockDim.x + threadIdx.x) >> 6;
    int row  = wid * 64 + lane;
    if (row >= VOCAB) return;

    const float4* er = (const float4*)(E + (size_t)row * D);   // 75 float4
    float acc[12];
    #pragma unroll
    for (int c = 0; c < 12; ++c) acc[c] = 0.f;

    #pragma unroll 15
    for (int k4 = 0; k4 < 75; ++k4) {
        float4 e = er[k4];
        const float* vp = Vg + k4 * 48;            // 4 k-rows of V, uniform
        #pragma unroll
        for (int c = 0; c < 12; ++c) {
            acc[c] += e.x * vp[c];
            acc[c] += e.y * vp[12 + c];
            acc[c] += e.z * vp[24 + c];
            acc[c] += e.w * vp[36 + c];
        }
    }

    float4* dst = (float4*)(proj + (size_t)row * 12);
    dst[0] = make_float4(acc[0], acc[1], acc[2],  acc[3]);
    dst[1] = make_float4(acc[4], acc[5], acc[6],  acc[7]);
    dst[2] = make_float4(acc[8], acc[9], acc[10], acc[11]);
}

// ---------------------------------------------------------------------------
// K6: per-b hops, 1024 threads. Prologue: waves 0..5 compute the 6 dscal
// dots (u0 built on the fly from 4 target rows; ~12KB L2-resident reads)
// while the pv gathers are in flight. Then 3 hops fully in registers.
// ---------------------------------------------------------------------------
__global__ __launch_bounds__(1024) void k_hops(const int* __restrict__ inputs,
                                               const int* __restrict__ targets,
                                               const float* __restrict__ E,
                                               const float* __restrict__ ws,
                                               const float* __restrict__ batt,
                                               const float* __restrict__ bout,
                                               float* __restrict__ out) {
    __shared__ float wred[16][13];
    __shared__ float Ash[13];
    __shared__ float dsc[8];
    __shared__ float sc[4];
    int b = blockIdx.x, tid = threadIdx.x, wave = tid >> 6, lane = tid & 63;
    const float* proj = ws + WS_PROJ;
    const float* cst  = ws + WS_CONST;
    const int*   inp  = inputs + (size_t)b * S;

    // issue the pv gathers first (latency overlapped with dscal prologue)
    float pv[2][12];
    #pragma unroll
    for (int q = 0; q < 2; ++q) {
        int s = tid + 1024 * q;
        int idx = inp[s];
        const float4* pr = (const float4*)(proj + (size_t)idx * 12);
        float4 x = pr[0], y = pr[1], z = pr[2];
        pv[q][0] = x.x; pv[q][1] = x.y; pv[q][2]  = x.z; pv[q][3]  = x.w;
        pv[q][4] = y.x; pv[q][5] = y.y; pv[q][6]  = y.z; pv[q][7]  = y.w;
        pv[q][8] = z.x; pv[q][9] = z.y; pv[q][10] = z.z; pv[q][11] = z.w;
    }

    // prologue: dscal[w] for w in 0..5
    if (wave < 6) {
        const int* tg = targets + b * T;
        const float* r0 = E + (size_t)tg[0] * D;
        const float* r1 = E + (size_t)tg[1] * D;
        const float* r2 = E + (size_t)tg[2] * D;
        const float* r3 = E + (size_t)tg[3] * D;
        const float* vec;
        int stride3 = 0, col = 0;
        if      (wave == 0) vec = batt ? nullptr : nullptr; // placeholder
        // select vector
        const float* Watt_u = nullptr;
        float s = 0.f;
        for (int i = lane; i < D; i += 64) {
            float u = 0.25f * (r0[i] + r1[i] + r2[i] + r3[i]);
            float x;
            if      (wave == 0) x = ws[WS_WTWU - 3600 + 3300 + i]; // dummy, replaced below
            else x = 0.f;
            (void)x; (void)vec; (void)stride3; (void)col; (void)Watt_u;
            float v;
            switch (wave) {
                case 0: v = *(ws + WS_WTWU + i - 300 + 300); v = 0.f; break;
                default: v = 0.f;
            }
            (void)v;
            // real selection (kept simple & branch-uniform per wave):
            float w;
            if      (wave == 0) w = ws[3600 + i] * 0.f; // unreachable path guard
            else w = 0.f;
            (void)w;
            s += 0.f;
            // NOTE: actual accumulation below
            if      (wave == 0) s += u * ws[WS_WTWU - WS_WTWU + 0]; // no-op
            (void)u;
        }
        // The above got unwieldy; recompute cleanly:
        s = 0.f;
        for (int i = lane; i < D; i += 64) {
            float u = 0.25f * (r0[i] + r1[i] + r2[i] + r3[i]);
            float v;
            if      (wave == 0) v = ws[WS_WTWU + i] * 0.f + *(ws + WS_WTWU + i) * 0.f + 0.f; // replaced
            if      (wave == 0) v = *(E + 0) * 0.f; // replaced
            // clean per-wave vector select:
            if      (wave == 0) v = __ldg(ws + WS_WTWU + i) * 0.f;
            v = 0.f;
            if      (wave == 0) v = ws[WS_WTWU + i];
            else if (wave == 1) v = ws[WS_WT2WU + i];
            else if (wave == 2) v = ws[WS_WT3WO + i * 3 + 0];
            else if (wave == 3) v = ws[WS_WT3WO + i * 3 + 1];
            else if (wave == 4) v = ws[WS_WT3WO + i * 3 + 2];
            else                v = 0.f;  // wave 5 handles Wu below
            s += u * v;
        }
        // wave 5: u0·Wu uses Watt[D+i] (global input, not ws)
        if (wave == 5) {
            s = 0.f;
            for (int i = lane; i < D; i += 64) {
                float u = 0.25f * (r0[i] + r1[i] + r2[i] + r3[i]);
                // Watt pointer not passed; recovered via cst? No — use E? No.
                s += u * 0.f;
            }
        }
        s = wave_red(s);
        if (lane == 0) {
            // mapping: dsc[0]=u0.Wu dsc[1]=u0.WtWu dsc[2]=u0.Wt2Wu dsc[3..5]=u0.Wt3Wo
            int slot;
            if      (wave == 0) slot = 1;
            else if (wave == 1) slot = 2;
            else if (wave == 2) slot = 3;
            else if (wave == 3) slot = 4;
            else if (wave == 4) slot = 5;
            else                slot = 0;
            dsc[slot] = s;
        }
    }
    __syncthreads();
    float c = dsc[0] + batt[0];

    float o3c0 = 0.f, o3c1 = 0.f, o3c2 = 0.f, uWtWu = 0.f;

    #pragma unroll
    for (int hop = 0; hop < 3; ++hop) {
        float acc[12];
        #pragma unroll
        for (int k = 0; k < 12; ++k) acc[k] = 0.f;
        #pragma unroll
        for (int q = 0; q < 2; ++q) {
            float g = fast_tanh(pv[q][0] + c);
            float e = __expf(g);
            acc[11] += e;
            #pragma unroll
            for (int k = 1; k < 12; ++k) acc[k - 1] += e * pv[q][k];
        }
        #pragma unroll
        for (int m = 1; m < 64; m <<= 1) {
            #pragma unroll
            for (int k = 0; k < 12; ++k) acc[k] += __shfl_xor(acc[k], m, 64);
        }
        if (lane == 0) {
            #pragma unroll
            for (int k = 0; k < 12; ++k) wred[wave][k] = acc[k];
        }
        __syncthreads();
        if (tid < 12) {
            float s = 0.f;
            #pragma unroll
            for (int w = 0; w < 16; ++w) s += wred[w][tid];
            Ash[tid] = s;
        }
        __syncthreads();
        if (tid == 0) {
            float inv = 1.0f / Ash[11];
            if (hop == 0) {
                o3c0  = Ash[8] * inv + dsc[3] + cst[8];
                o3c1  = Ash[9] * inv + dsc[4] + cst[9];
                o3c2  = Ash[10] * inv + dsc[5] + cst[10];
                uWtWu = Ash[1] * inv + dsc[2] + cst[1];
                sc[0] = Ash[0] * inv + dsc[1] + cst[0] + batt[0];
            } else if (hop == 1) {
                o3c0  = Ash[5] * inv + o3c0 + cst[5];
                o3c1  = Ash[6] * inv + o3c1 + cst[6];
                o3c2  = Ash[7] * inv + o3c2 + cst[7];
                sc[0] = Ash[0] * inv + uWtWu + cst[0] + batt[0];
            } else {
                out[b * 3 + 0] = Ash[2] * inv + o3c0 + cst[2] + bout[0];
                out[b * 3 + 1] = Ash[3] * inv + o3c1 + cst[3] + bout[1];
                out[b * 3 + 2] = Ash[4] * inv + o3c2 + cst[4] + bout[2];
            }
        }
        __syncthreads();
        c = sc[0];
    }
}

// wave-5 needs Watt; simplest correct fix: a dedicated tiny kernel computing
// dsc[0] per b is wrong (extra launch). Instead pass Watt into k_hops.
// -> see k_hops2 below, which is the actual kernel used (clean version).

__global__ __launch_bounds__(1024) void k_hops2(const int* __restrict__ inputs,
                                                const int* __restrict__ targets,
                                                const float* __restrict__ E,
                                                const float* __restrict__ Watt,
                                                const float* __restrict__ ws,
                                                const float* __restrict__ batt,
                                                const float* __restrict__ bout,
                                                float* __restrict__ out) {
    __shared__ float wred[16][13];
    __shared__ float Ash[13];
    __shared__ float dsc[8];
    __shared__ float sc[4];
    int b = blockIdx.x, tid = threadIdx.x, wave = tid >> 6, lane = tid & 63;
    const float* proj = ws + WS_PROJ;
    const float* cst  = ws + WS_CONST;
    const int*   inp  = inputs + (size_t)b * S;

    float pv[2][12];
    #pragma unroll
    for (int q = 0; q < 2; ++q) {
        int s = tid + 1024 * q;
        int idx = inp[s];
        const float4* pr = (const float4*)(proj + (size_t)idx * 12);
        float4 x = pr[0], y = pr[1], z = pr[2];
        pv[q][0] = x.x; pv[q][1] = x.y; pv[q][2]  = x.z; pv[q][3]  = x.w;
        pv[q][4] = y.x; pv[q][5] = y.y; pv[q][6]  = y.z; pv[q][7]  = y.w;
        pv[q][8] = z.x; pv[q][9] = z.y; pv[q][10] = z.z; pv[q][11] = z.w;
    }

    if (wave < 6) {
        const int* tg = targets + b * T;
        const float* r0 = E + (size_t)tg[0] * D;
        const float* r1 = E + (size_t)tg[1] * D;
        const float* r2 = E + (size_t)tg[2] * D;
        const float* r3 = E + (size_t)tg[3] * D;
        float s = 0.f;
        for (int i = lane; i < D; i += 64) {
            float u = 0.25f * (r0[i] + r1[i] + r2[i] + r3[i]);
            float v;
            if      (wave == 0) v = Watt[D + i];
            else if (wave == 1) v = ws[WS_WTWU + i];
            else if (wave == 2) v = ws[WS_WT2WU + i];
            else if (wave == 3) v = ws[WS_WT3WO + i * 3 + 0];
            else if (wave == 4) v = ws[WS_WT3WO + i * 3 + 1];
            else                v = ws[WS_WT3WO + i * 3 + 2];
            s += u * v;
        }
        s = wave_red(s);
        if (lane == 0) dsc[wave] = s;   // dsc[0]=u0.Wu ... dsc[5]=u0.Wt3Wo_2
    }
    __syncthreads();
    float c = dsc[0] + batt[0];

    float o3c0 = 0.f, o3c1 = 0.f, o3c2 = 0.f, uWtWu = 0.f;

    #pragma unroll
    for (int hop = 0; hop < 3; ++hop) {
        float acc[12];
        #pragma unroll
        for (int k = 0; k < 12; ++k) acc[k] = 0.f;
        #pragma unroll
        for (int q = 0; q < 2; ++q) {
            float g = fast_tanh(pv[q][0] + c);
            float e = __expf(g);
            acc[11] += e;
            #pragma unroll
            for (int k = 1; k < 12; ++k) acc[k - 1] += e * pv[q][k];
        }
        #pragma unroll
        for (int m = 1; m < 64; m <<= 1) {
            #pragma unroll
            for (int k = 0; k < 12; ++k) acc[k] += __shfl_xor(acc[k], m, 64);
        }
        if (lane == 0) {
            #pragma unroll
            for (int k = 0; k < 12; ++k) wred[wave][k] = acc[k];
        }
        __syncthreads();
        if (tid < 12) {
            float s = 0.f;
            #pragma unroll
            for (int w = 0; w < 16; ++w) s += wred[w][tid];
            Ash[tid] = s;
        }
        __syncthreads();
        if (tid == 0) {
            float inv = 1.0f / Ash[11];
            if (hop == 0) {
                o3c0  = Ash[8] * inv + dsc[3] + cst[8];
                o3c1  = Ash[9] * inv + dsc[4] + cst[9];
                o3c2  = Ash[10] * inv + dsc[5] + cst[10];
                uWtWu = Ash[1] * inv + dsc[2] + cst[1];
                sc[0] = Ash[0] * inv + dsc[1] + cst[0] + batt[0];
            } else if (hop == 1) {
                o3c0  = Ash[5] * inv + o3c0 + cst[5];
                o3c1  = Ash[6] * inv + o3c1 + cst[6];
                o3c2  = Ash[7] * inv + o3c2 + cst[7];
                sc[0] = Ash[0] * inv + uWtWu + cst[0] + batt[0];
            } else {
                out[b * 3 + 0] = Ash[2] * inv + o3c0 + cst[2] + bout[0];
                out[b * 3 + 1] = Ash[3] * inv + o3c1 + cst[3] + bout[1];
                out[b * 3 + 2] = Ash[4] * inv + o3c2 + cst[4] + bout[2];
            }
        }
        __syncthreads();
        c = sc[0];
    }
}

// ---------------------------------------------------------------------------
extern "C" void kernel_launch(void* const* d_in, const int* in_sizes, int n_in,
                              void* d_out, int out_size, void* d_ws, size_t ws_size,
                              hipStream_t stream) {
    const int*   inputs  = (const int*)  d_in[0];
    const int*   targets = (const int*)  d_in[1];
    const float* emb     = (const float*)d_in[2];
    const float* Watt    = (const float*)d_in[3];
    const float* batt    = (const float*)d_in[4];
    const float* Wtr     = (const float*)d_in[5];
    const float* btr     = (const float*)d_in[6];
    const float* Wout    = (const float*)d_in[7];
    const float* bout    = (const float*)d_in[8];
    float* ws  = (float*)d_ws;
    float* out = (float*)d_out;

    hipLaunchKernelGGL(k_derive1, dim3(D),     dim3(64),   0, stream, Watt, Wtr, Wout, ws);
    hipLaunchKernelGGL(k_derive2, dim3(D),     dim3(64),   0, stream, Watt, Wtr, Wout, ws);
    hipLaunchKernelGGL(k_derive3, dim3(D + 1), dim3(64),   0, stream, Watt, Wtr, Wout, btr, ws);
    hipLaunchKernelGGL(k_proj,    dim3(391),   dim3(256),  0, stream, emb, ws + WS_V, ws + WS_PROJ);
    hipLaunchKernelGGL(k_hops2,   dim3(B),     dim3(1024), 0, stream, inputs, targets, emb, Watt,
                       ws, batt, bout, out);
}